// Round 1
// 1094.384 us; speedup vs baseline: 1.3471x; 1.3471x over previous
//
#include <hip/hip_runtime.h>
#include <cstdint>
#include <cstddef>

// SparseMoE MI355X gfx950. ALL I/O FP32; bf16 MFMA internally.
// v2: (1) contended-atomic gating removed (ballot count + wave-aggregated scatter),
//     (2) big-ws path: bf16 pre-convert of xl + per-chunk transposed W1/W2 panels ->
//         pure-bf16 GEMM with global_load_lds(16B) and XOR-swizzled LDS (m97/m173/m201),
//     (3) fallback path keeps fp32-convert ffn kernels but fixes the As bank conflict.
//
// ws big (~84.0 MB): Hc 33.5M | xlb 16.8M | w1c 16.8M | w2c 16.8M | list 64K | eids 32K | meta 4K
// ws small (~33.7 MB): Hc 33.5M | list 64K | eids 32K | meta 4K   (previous layout)

#define TOKENS 8192
#define DM 1024
#define DH 4096
#define NE 8
#define CHUNK 1024
#define NCHUNK 4
#define MAXTILES 160

typedef __attribute__((ext_vector_type(8))) short short8;
typedef __attribute__((ext_vector_type(4))) float f32x4;
typedef unsigned short u16;
typedef unsigned int u32;
typedef unsigned long long u64;

__device__ __forceinline__ u16 f2bf(float f) {
  u32 u = __builtin_bit_cast(u32, f);
  u += 0x7fffu + ((u >> 16) & 1u);  // RNE
  return (u16)(u >> 16);
}

// async global->LDS, 16B per lane. LDS dest is wave-uniform base + lane*16 (m104).
__device__ __forceinline__ void gl2lds16(const void* g, void* l) {
  __builtin_amdgcn_global_load_lds(
      (const __attribute__((address_space(1))) void*)g,
      (__attribute__((address_space(3))) void*)l, 16, 0, 0);
}

// ---------------- gating: top-2 of fp32 logits (softmax monotone, gates > 0).
// NO atomics here (v1's 16384 same-cacheline atomicAdds = ~200us drain).
__global__ __launch_bounds__(256) void gate_topk(
    const float* __restrict__ x0, const float* __restrict__ Wg,
    int* __restrict__ eids) {
  const int wave = threadIdx.x >> 6;
  const int lane = threadIdx.x & 63;
  const int t = blockIdx.x * 4 + wave;
  const float* xrow = x0 + (size_t)t * DM + lane * 16;
  float xs[16];
#pragma unroll
  for (int q = 0; q < 4; ++q) *(float4*)(xs + q * 4) = *(const float4*)(xrow + q * 4);
  float s[NE] = {0.f, 0.f, 0.f, 0.f, 0.f, 0.f, 0.f, 0.f};
#pragma unroll
  for (int j = 0; j < 16; ++j) {
    const float* wrow = Wg + (size_t)(lane * 16 + j) * NE;
    float w[8];
    *(float4*)(w) = *(const float4*)(wrow);
    *(float4*)(w + 4) = *(const float4*)(wrow + 4);
#pragma unroll
    for (int e = 0; e < NE; ++e) s[e] += xs[j] * w[e];
  }
#pragma unroll
  for (int off = 32; off > 0; off >>= 1)
#pragma unroll
    for (int e = 0; e < NE; ++e) s[e] += __shfl_down(s[e], off);
  if (lane == 0) {
    int a1 = 0; float v1 = s[0];
#pragma unroll
    for (int e = 1; e < NE; ++e) if (s[e] > v1) { v1 = s[e]; a1 = e; }  // first-index ties
    int a2 = -1; float v2 = 0.f; bool init = false;
#pragma unroll
    for (int e = 0; e < NE; ++e) {
      if (e == a1) continue;
      if (!init || s[e] > v2) { v2 = s[e]; a2 = e; init = true; }
    }
    eids[t] = a1 | (a2 << 8);
  }
}

// counts (ballot/popc, no atomics) + offsets/cursors + expert-pure 128-row tile list.
__global__ __launch_bounds__(256) void count_prefix(
    const int* __restrict__ eids, int* __restrict__ counts, int* __restrict__ offsets,
    int* __restrict__ cursors, int* __restrict__ n_tiles,
    int* __restrict__ tile_e, int* __restrict__ tile_row0) {
  __shared__ int wc[4][NE];
  const int lane = threadIdx.x & 63;
  const int wave = threadIdx.x >> 6;
  int c[NE] = {0, 0, 0, 0, 0, 0, 0, 0};
  for (int t = threadIdx.x; t < TOKENS; t += 256) {  // all lanes active: 8192 % 256 == 0
    int p = eids[t];
    int a1 = p & 255, a2 = (p >> 8) & 255;
#pragma unroll
    for (int e = 0; e < NE; ++e)
      c[e] += __popcll(__ballot(a1 == e)) + __popcll(__ballot(a2 == e));
  }
  if (lane == 0)
#pragma unroll
    for (int e = 0; e < NE; ++e) wc[wave][e] = c[e];
  __syncthreads();
  if (threadIdx.x == 0) {
    int o = 0, nt = 0;
    for (int e = 0; e < NE; ++e) {
      int ce = wc[0][e] + wc[1][e] + wc[2][e] + wc[3][e];
      counts[e] = ce; offsets[e] = o; cursors[e] = o;
      for (int r = 0; r < ce; r += 128) { tile_e[nt] = e; tile_row0[nt] = r; ++nt; }
      o += ce;
    }
    *n_tiles = nt;
  }
}

// wave-aggregated scatter: 1 atomic per (wave, expert) = 1024 total (was 16384).
__global__ __launch_bounds__(256) void scatter_tokens(
    const int* __restrict__ eids, int* __restrict__ cursors, int* __restrict__ list) {
  const int t = blockIdx.x * 256 + threadIdx.x;   // grid exactly covers TOKENS
  const int lane = threadIdx.x & 63;
  const int p = eids[t];
  const int a1 = p & 255, a2 = (p >> 8) & 255;
  const u64 lt = (1ull << lane) - 1ull;
#pragma unroll
  for (int e = 0; e < NE; ++e) {
    u64 b1 = __ballot(a1 == e);
    u64 b2 = __ballot(a2 == e);
    int tot = __popcll(b1) + __popcll(b2);
    int base = 0;
    if (lane == 0 && tot) base = atomicAdd(&cursors[e], tot);
    base = __shfl(base, 0);
    if (a1 == e) list[base + __popcll(b1 & lt)] = t;
    if (a2 == e) list[base + __popcll(b1) + __popcll(b2 & lt)] = t;
  }
}

// ================= big-ws path: bf16 pre-conversion =================

__global__ __launch_bounds__(256) void conv_xl_kernel(
    const float* __restrict__ x, u16* __restrict__ xb) {
  size_t i = ((size_t)blockIdx.x * 256 + threadIdx.x) * 8;
  float4 a = *(const float4*)(x + i);
  float4 b = *(const float4*)(x + i + 4);
  u16 h[8];
  h[0] = f2bf(a.x); h[1] = f2bf(a.y); h[2] = f2bf(a.z); h[3] = f2bf(a.w);
  h[4] = f2bf(b.x); h[5] = f2bf(b.y); h[6] = f2bf(b.z); h[7] = f2bf(b.w);
  *(uint4*)(xb + i) = *(uint4*)h;
}

// W1 [e][DM][DH] fp32 -> w1c [e][n<CHUNK][k<DM] bf16 (transposed chunk panel)
__global__ __launch_bounds__(256) void conv_w1_kernel(
    const float* __restrict__ W1, u16* __restrict__ w1c, int cb) {
  __shared__ float tile[32][33];
  const int e = blockIdx.z;
  const int n0 = blockIdx.x * 32;
  const int k0 = blockIdx.y * 32;
  const int tx = threadIdx.x & 31;
  const int ty = threadIdx.x >> 5;  // 0..7
#pragma unroll
  for (int j = 0; j < 4; ++j)
    tile[ty + j * 8][tx] = W1[((size_t)e * DM + k0 + ty + j * 8) * DH + cb + n0 + tx];
  __syncthreads();
#pragma unroll
  for (int j = 0; j < 4; ++j)
    w1c[((size_t)e * CHUNK + n0 + ty + j * 8) * DM + k0 + tx] = f2bf(tile[tx][ty + j * 8]);
}

// W2 [e][DH][DM] fp32 -> w2c [e][n<DM][k<CHUNK] bf16 (transposed chunk panel)
__global__ __launch_bounds__(256) void conv_w2_kernel(
    const float* __restrict__ W2, u16* __restrict__ w2c, int cb) {
  __shared__ float tile[32][33];
  const int e = blockIdx.z;
  const int n0 = blockIdx.x * 32;
  const int k0 = blockIdx.y * 32;
  const int tx = threadIdx.x & 31;
  const int ty = threadIdx.x >> 5;
#pragma unroll
  for (int j = 0; j < 4; ++j)
    tile[ty + j * 8][tx] = W2[((size_t)e * DH + cb + k0 + ty + j * 8) * DM + n0 + tx];
  __syncthreads();
#pragma unroll
  for (int j = 0; j < 4; ++j)
    w2c[((size_t)e * DM + n0 + ty + j * 8) * CHUNK + k0 + tx] = f2bf(tile[tx][ty + j * 8]);
}

// bf16 GEMM tile, m97 structure: 128x128, BK=64, global_load_lds(16B), linear LDS with
// XOR swizzle realized by pre-swizzling the per-lane GLOBAL source (rule #21):
//   LDS[r][q] holds global chunk q ^ (r&7); fragment reads XOR the chunk index back.
// A-operand rows come from a gather list (per-lane global addresses are allowed).
__global__ __launch_bounds__(256) void ffn1b_kernel(
    const u16* __restrict__ xlb, const u16* __restrict__ w1c,
    const float* __restrict__ b1, const int* __restrict__ list,
    const int* __restrict__ counts, const int* __restrict__ offsets,
    const int* __restrict__ n_tiles, const int* __restrict__ tile_e,
    const int* __restrict__ tile_row0, u16* __restrict__ Hc, int cbase) {
  const int ti = blockIdx.y;
  if (ti >= *n_tiles) return;
  const int e = tile_e[ti];
  const int row0 = tile_row0[ti];
  const int cnt = counts[e];
  const int off = offsets[e];
  const int n0 = blockIdx.x * 128;

  __shared__ u16 As[128 * 64];
  __shared__ u16 Bs[128 * 64];

  const int tid = threadIdx.x;
  const int lane = tid & 63;
  const int wave = tid >> 6;
  const int wm = (wave & 1) * 64;
  const int wn = (wave >> 1) * 64;

  const int srow = lane >> 3;                      // row within 8-row group; == r&7
  const int schunk = ((lane & 7) ^ srow) << 3;     // pre-swizzled source chunk (elems)

  const u16* aptr[4];
#pragma unroll
  for (int i = 0; i < 4; ++i) {
    int rr = row0 + wave * 32 + i * 8 + srow;
    if (rr >= cnt) rr = cnt - 1;                   // clamp; stores guarded later
    int tok = list[off + rr];
    aptr[i] = xlb + (size_t)tok * DM + schunk;
  }
  const u16* bptr = w1c + ((size_t)e * CHUNK + n0 + wave * 32 + srow) * DM + schunk;

  f32x4 acc[4][4];
#pragma unroll
  for (int mi = 0; mi < 4; ++mi)
#pragma unroll
    for (int ni = 0; ni < 4; ++ni) acc[mi][ni] = (f32x4){0.f, 0.f, 0.f, 0.f};

  for (int k0 = 0; k0 < DM; k0 += 64) {
#pragma unroll
    for (int i = 0; i < 4; ++i) {
      gl2lds16(aptr[i] + k0, &As[(wave * 32 + i * 8) * 64]);
      gl2lds16(bptr + (size_t)(i * 8) * DM + k0, &Bs[(wave * 32 + i * 8) * 64]);
    }
    __syncthreads();
#pragma unroll
    for (int s = 0; s < 2; ++s) {
      const int G = s * 4 + (lane >> 4);           // global 16B-chunk index
      short8 af[4], bfr[4];
#pragma unroll
      for (int mi = 0; mi < 4; ++mi) {
        int r = wm + mi * 16 + (lane & 15);
        af[mi] = *(const short8*)(&As[r * 64 + ((G ^ (r & 7)) << 3)]);
      }
#pragma unroll
      for (int ni = 0; ni < 4; ++ni) {
        int r = wn + ni * 16 + (lane & 15);
        bfr[ni] = *(const short8*)(&Bs[r * 64 + ((G ^ (r & 7)) << 3)]);
      }
#pragma unroll
      for (int mi = 0; mi < 4; ++mi)
#pragma unroll
        for (int ni = 0; ni < 4; ++ni)
          acc[mi][ni] = __builtin_amdgcn_mfma_f32_16x16x32_bf16(af[mi], bfr[ni], acc[mi][ni], 0, 0, 0);
    }
    __syncthreads();
  }

  float bb[4];
#pragma unroll
  for (int ni = 0; ni < 4; ++ni)
    bb[ni] = b1[e * DH + cbase + n0 + wn + ni * 16 + (lane & 15)];
#pragma unroll
  for (int mi = 0; mi < 4; ++mi) {
#pragma unroll
    for (int r = 0; r < 4; ++r) {
      int rrow = row0 + wm + mi * 16 + (lane >> 4) * 4 + r;
      if (rrow < cnt) {
        u16* h = Hc + (size_t)(off + rrow) * CHUNK + n0 + wn + (lane & 15);
#pragma unroll
        for (int ni = 0; ni < 4; ++ni) {
          float v = acc[mi][ni][r] + bb[ni];
          h[ni * 16] = f2bf(v > 0.f ? v : 0.f);
        }
      }
    }
  }
}

__global__ __launch_bounds__(256) void ffn2b_kernel(
    const u16* __restrict__ Hc, const u16* __restrict__ w2c,
    const float* __restrict__ b2, const int* __restrict__ list,
    const int* __restrict__ counts, const int* __restrict__ offsets,
    const int* __restrict__ n_tiles, const int* __restrict__ tile_e,
    const int* __restrict__ tile_row0, float* __restrict__ out, int cbase) {
  const int ti = blockIdx.y;
  if (ti >= *n_tiles) return;
  const int e = tile_e[ti];
  const int row0 = tile_row0[ti];
  const int cnt = counts[e];
  const int off = offsets[e];
  const int n0 = blockIdx.x * 128;

  __shared__ u16 As[128 * 64];
  __shared__ u16 Bs[128 * 64];

  const int tid = threadIdx.x;
  const int lane = tid & 63;
  const int wave = tid >> 6;
  const int wm = (wave & 1) * 64;
  const int wn = (wave >> 1) * 64;

  const int srow = lane >> 3;
  const int schunk = ((lane & 7) ^ srow) << 3;

  const u16* aptr[4];
#pragma unroll
  for (int i = 0; i < 4; ++i) {
    int rr = row0 + wave * 32 + i * 8 + srow;
    if (rr >= cnt) rr = cnt - 1;
    aptr[i] = Hc + (size_t)(off + rr) * CHUNK + schunk;
  }
  const u16* bptr = w2c + ((size_t)e * DM + n0 + wave * 32 + srow) * CHUNK + schunk;

  f32x4 acc[4][4];
#pragma unroll
  for (int mi = 0; mi < 4; ++mi)
#pragma unroll
    for (int ni = 0; ni < 4; ++ni) acc[mi][ni] = (f32x4){0.f, 0.f, 0.f, 0.f};

  for (int k0 = 0; k0 < CHUNK; k0 += 64) {
#pragma unroll
    for (int i = 0; i < 4; ++i) {
      gl2lds16(aptr[i] + k0, &As[(wave * 32 + i * 8) * 64]);
      gl2lds16(bptr + (size_t)(i * 8) * CHUNK + k0, &Bs[(wave * 32 + i * 8) * 64]);
    }
    __syncthreads();
#pragma unroll
    for (int s = 0; s < 2; ++s) {
      const int G = s * 4 + (lane >> 4);
      short8 af[4], bfr[4];
#pragma unroll
      for (int mi = 0; mi < 4; ++mi) {
        int r = wm + mi * 16 + (lane & 15);
        af[mi] = *(const short8*)(&As[r * 64 + ((G ^ (r & 7)) << 3)]);
      }
#pragma unroll
      for (int ni = 0; ni < 4; ++ni) {
        int r = wn + ni * 16 + (lane & 15);
        bfr[ni] = *(const short8*)(&Bs[r * 64 + ((G ^ (r & 7)) << 3)]);
      }
#pragma unroll
      for (int mi = 0; mi < 4; ++mi)
#pragma unroll
        for (int ni = 0; ni < 4; ++ni)
          acc[mi][ni] = __builtin_amdgcn_mfma_f32_16x16x32_bf16(af[mi], bfr[ni], acc[mi][ni], 0, 0, 0);
    }
    __syncthreads();
  }

  float bb[4];
#pragma unroll
  for (int ni = 0; ni < 4; ++ni)
    bb[ni] = (cbase == 0) ? b2[e * DM + n0 + wn + ni * 16 + (lane & 15)] : 0.f;
#pragma unroll
  for (int mi = 0; mi < 4; ++mi) {
#pragma unroll
    for (int r = 0; r < 4; ++r) {
      int rrow = row0 + wm + mi * 16 + (lane >> 4) * 4 + r;
      if (rrow < cnt) {
        int tok = list[off + rrow];
        float* ar = out + (size_t)tok * DM + n0 + wn + (lane & 15);
#pragma unroll
        for (int ni = 0; ni < 4; ++ni)
          atomicAdd(&ar[ni * 16], acc[mi][ni][r] + bb[ni]);
      }
    }
  }
}

// ================= fallback path (small ws): fp32 weights converted in-kernel.
// v2 change: As 16B-chunk XOR swizzle kills the 16-lane/bank-quad conflict on A reads.

__global__ __launch_bounds__(256) void ffn1_kernel(
    const float* __restrict__ xl, const float* __restrict__ W1,
    const float* __restrict__ b1, const int* __restrict__ list,
    const int* __restrict__ counts, const int* __restrict__ offsets,
    const int* __restrict__ n_tiles, const int* __restrict__ tile_e,
    const int* __restrict__ tile_row0, u16* __restrict__ Hc, int cbase) {
  const int ti = blockIdx.y;
  if (ti >= *n_tiles) return;
  const int e = tile_e[ti];
  const int row0 = tile_row0[ti];
  const int cnt = counts[e];
  const int off = offsets[e];
  const int n0 = blockIdx.x * 128;

  __shared__ u16 As[128 * 64];
  __shared__ u16 Bs[128 * 66];

  const int tid = threadIdx.x;
  const int lane = tid & 63;
  const int wave = tid >> 6;

  const float* arow[4];
#pragma unroll
  for (int p = 0; p < 4; ++p) {
    int rr = row0 + p * 32 + (tid >> 3);
    if (rr >= cnt) rr = cnt - 1;
    int tok = list[off + rr];
    arow[p] = xl + (size_t)tok * DM + ((tid & 7) << 3);
  }
  const float* gB = W1 + (size_t)e * DM * DH + cbase + n0;
  const int k2 = (tid >> 4) * 2;
  const int ncol = (tid & 15) * 8;
  const int aq = (((tid & 7) ^ ((tid >> 3) & 7)) << 3);  // swizzled A chunk

  f32x4 acc[4][4];
#pragma unroll
  for (int mi = 0; mi < 4; ++mi)
#pragma unroll
    for (int ni = 0; ni < 4; ++ni) acc[mi][ni] = (f32x4){0.f, 0.f, 0.f, 0.f};

  const int wm = (wave & 1) * 64;
  const int wn = (wave >> 1) * 64;

  for (int k0 = 0; k0 < DM; k0 += 64) {
#pragma unroll
    for (int p = 0; p < 4; ++p) {
      float4 v0 = *(const float4*)(arow[p] + k0);
      float4 v1 = *(const float4*)(arow[p] + k0 + 4);
      u16 h[8];
      h[0] = f2bf(v0.x); h[1] = f2bf(v0.y); h[2] = f2bf(v0.z); h[3] = f2bf(v0.w);
      h[4] = f2bf(v1.x); h[5] = f2bf(v1.y); h[6] = f2bf(v1.z); h[7] = f2bf(v1.w);
      *(uint4*)(&As[(p * 32 + (tid >> 3)) * 64 + aq]) = *(uint4*)h;
    }
#pragma unroll
    for (int p = 0; p < 2; ++p) {
      int k = k2 + p * 32;
      const float* s0 = gB + (size_t)(k0 + k) * DH + ncol;
      const float* s1 = s0 + DH;
      float r0[8], r1[8];
      *(float4*)(r0) = *(const float4*)(s0);
      *(float4*)(r0 + 4) = *(const float4*)(s0 + 4);
      *(float4*)(r1) = *(const float4*)(s1);
      *(float4*)(r1 + 4) = *(const float4*)(s1 + 4);
#pragma unroll
      for (int j = 0; j < 8; ++j) {
        u32 w32 = (u32)f2bf(r0[j]) | ((u32)f2bf(r1[j]) << 16);
        *(u32*)(&Bs[(ncol + j) * 66 + k]) = w32;
      }
    }
    __syncthreads();
#pragma unroll
    for (int s = 0; s < 2; ++s) {
      const int G = s * 4 + (lane >> 4);
      const int kk = s * 32 + (lane >> 4) * 8;
      short8 af[4], bfr[4];
#pragma unroll
      for (int mi = 0; mi < 4; ++mi) {
        int r = wm + mi * 16 + (lane & 15);
        af[mi] = *(const short8*)(&As[r * 64 + ((G ^ (r & 7)) << 3)]);
      }
#pragma unroll
      for (int ni = 0; ni < 4; ++ni) {
        const u32* bp = (const u32*)(&Bs[(wn + ni * 16 + (lane & 15)) * 66 + kk]);
        union { u32 u[4]; short8 v; } bu;
        bu.u[0] = bp[0]; bu.u[1] = bp[1]; bu.u[2] = bp[2]; bu.u[3] = bp[3];
        bfr[ni] = bu.v;
      }
#pragma unroll
      for (int mi = 0; mi < 4; ++mi)
#pragma unroll
        for (int ni = 0; ni < 4; ++ni)
          acc[mi][ni] = __builtin_amdgcn_mfma_f32_16x16x32_bf16(af[mi], bfr[ni], acc[mi][ni], 0, 0, 0);
    }
    __syncthreads();
  }

  float bb[4];
#pragma unroll
  for (int ni = 0; ni < 4; ++ni)
    bb[ni] = b1[e * DH + cbase + n0 + wn + ni * 16 + (lane & 15)];
#pragma unroll
  for (int mi = 0; mi < 4; ++mi) {
#pragma unroll
    for (int r = 0; r < 4; ++r) {
      int rrow = row0 + wm + mi * 16 + (lane >> 4) * 4 + r;
      if (rrow < cnt) {
        u16* h = Hc + (size_t)(off + rrow) * CHUNK + n0 + wn + (lane & 15);
#pragma unroll
        for (int ni = 0; ni < 4; ++ni) {
          float v = acc[mi][ni][r] + bb[ni];
          h[ni * 16] = f2bf(v > 0.f ? v : 0.f);
        }
      }
    }
  }
}

__global__ __launch_bounds__(256) void ffn2_kernel(
    const u16* __restrict__ Hc, const float* __restrict__ W2,
    const float* __restrict__ b2, const int* __restrict__ list,
    const int* __restrict__ counts, const int* __restrict__ offsets,
    const int* __restrict__ n_tiles, const int* __restrict__ tile_e,
    const int* __restrict__ tile_row0, float* __restrict__ out, int cbase) {
  const int ti = blockIdx.y;
  if (ti >= *n_tiles) return;
  const int e = tile_e[ti];
  const int row0 = tile_row0[ti];
  const int cnt = counts[e];
  const int off = offsets[e];
  const int n0 = blockIdx.x * 128;

  __shared__ u16 As[128 * 64];
  __shared__ u16 Bs[128 * 66];

  const int tid = threadIdx.x;
  const int lane = tid & 63;
  const int wave = tid >> 6;

  const u16* arow[4];
#pragma unroll
  for (int p = 0; p < 4; ++p) {
    int rr = row0 + p * 32 + (tid >> 3);
    if (rr >= cnt) rr = cnt - 1;
    arow[p] = Hc + (size_t)(off + rr) * CHUNK + ((tid & 7) << 3);
  }
  const float* gB = W2 + (size_t)e * DH * DM + n0;
  const int k2 = (tid >> 4) * 2;
  const int ncol = (tid & 15) * 8;
  const int aq = (((tid & 7) ^ ((tid >> 3) & 7)) << 3);

  f32x4 acc[4][4];
#pragma unroll
  for (int mi = 0; mi < 4; ++mi)
#pragma unroll
    for (int ni = 0; ni < 4; ++ni) acc[mi][ni] = (f32x4){0.f, 0.f, 0.f, 0.f};

  const int wm = (wave & 1) * 64;
  const int wn = (wave >> 1) * 64;

  for (int k0 = 0; k0 < CHUNK; k0 += 64) {
#pragma unroll
    for (int p = 0; p < 4; ++p) {
      uint4 v = *(const uint4*)(arow[p] + k0);
      *(uint4*)(&As[(p * 32 + (tid >> 3)) * 64 + aq]) = v;
    }
#pragma unroll
    for (int p = 0; p < 2; ++p) {
      int k = k2 + p * 32;
      const float* s0 = gB + (size_t)(cbase + k0 + k) * DM + ncol;
      const float* s1 = s0 + DM;
      float r0[8], r1[8];
      *(float4*)(r0) = *(const float4*)(s0);
      *(float4*)(r0 + 4) = *(const float4*)(s0 + 4);
      *(float4*)(r1) = *(const float4*)(s1);
      *(float4*)(r1 + 4) = *(const float4*)(s1 + 4);
#pragma unroll
      for (int j = 0; j < 8; ++j) {
        u32 w32 = (u32)f2bf(r0[j]) | ((u32)f2bf(r1[j]) << 16);
        *(u32*)(&Bs[(ncol + j) * 66 + k]) = w32;
      }
    }
    __syncthreads();
#pragma unroll
    for (int s = 0; s < 2; ++s) {
      const int G = s * 4 + (lane >> 4);
      const int kk = s * 32 + (lane >> 4) * 8;
      short8 af[4], bfr[4];
#pragma unroll
      for (int mi = 0; mi < 4; ++mi) {
        int r = wm + mi * 16 + (lane & 15);
        af[mi] = *(const short8*)(&As[r * 64 + ((G ^ (r & 7)) << 3)]);
      }
#pragma unroll
      for (int ni = 0; ni < 4; ++ni) {
        const u32* bp = (const u32*)(&Bs[(wn + ni * 16 + (lane & 15)) * 66 + kk]);
        union { u32 u[4]; short8 v; } bu;
        bu.u[0] = bp[0]; bu.u[1] = bp[1]; bu.u[2] = bp[2]; bu.u[3] = bp[3];
        bfr[ni] = bu.v;
      }
#pragma unroll
      for (int mi = 0; mi < 4; ++mi)
#pragma unroll
        for (int ni = 0; ni < 4; ++ni)
          acc[mi][ni] = __builtin_amdgcn_mfma_f32_16x16x32_bf16(af[mi], bfr[ni], acc[mi][ni], 0, 0, 0);
    }
    __syncthreads();
  }

  float bb[4];
#pragma unroll
  for (int ni = 0; ni < 4; ++ni)
    bb[ni] = (cbase == 0) ? b2[e * DM + n0 + wn + ni * 16 + (lane & 15)] : 0.f;
#pragma unroll
  for (int mi = 0; mi < 4; ++mi) {
#pragma unroll
    for (int r = 0; r < 4; ++r) {
      int rrow = row0 + wm + mi * 16 + (lane >> 4) * 4 + r;
      if (rrow < cnt) {
        int tok = list[off + rrow];
        float* ar = out + (size_t)tok * DM + n0 + wn + (lane & 15);
#pragma unroll
        for (int ni = 0; ni < 4; ++ni)
          atomicAdd(&ar[ni * 16], acc[mi][ni][r] + bb[ni]);
      }
    }
  }
}

extern "C" void kernel_launch(void* const* d_in, const int* in_sizes, int n_in,
                              void* d_out, int out_size, void* d_ws, size_t ws_size,
                              hipStream_t stream) {
  const float* xl = (const float*)d_in[0];
  const float* x0 = (const float*)d_in[1];
  const float* Wg = (const float*)d_in[2];
  const float* W1 = (const float*)d_in[3];
  const float* b1 = (const float*)d_in[4];
  const float* W2 = (const float*)d_in[5];
  const float* b2 = (const float*)d_in[6];
  float* out = (float*)d_out;

  char* ws = (char*)d_ws;
  const size_t SZ_HC = (size_t)2 * TOKENS * CHUNK * 2;      // 33554432
  const size_t SZ_XLB = (size_t)TOKENS * DM * 2;            // 16777216
  const size_t SZ_W1C = (size_t)NE * CHUNK * DM * 2;        // 16777216
  const size_t SZ_W2C = (size_t)NE * DM * CHUNK * 2;        // 16777216
  const size_t SZ_LIST = 65536, SZ_EIDS = 32768, SZ_META = 4096;
  const bool big = ws_size >= SZ_HC + SZ_XLB + SZ_W1C + SZ_W2C + SZ_LIST + SZ_EIDS + SZ_META;

  u16* Hc = (u16*)ws;
  u16 *xlb = nullptr, *w1c = nullptr, *w2c = nullptr;
  int *list, *eids, *meta;
  if (big) {
    xlb = (u16*)(ws + SZ_HC);
    w1c = (u16*)(ws + SZ_HC + SZ_XLB);
    w2c = (u16*)(ws + SZ_HC + SZ_XLB + SZ_W1C);
    list = (int*)(ws + SZ_HC + SZ_XLB + SZ_W1C + SZ_W2C);
  } else {
    list = (int*)(ws + SZ_HC);
  }
  eids = (int*)((char*)list + SZ_LIST);
  meta = (int*)((char*)eids + SZ_EIDS);
  int* counts = meta;
  int* offsets = meta + 8;
  int* cursors = meta + 16;
  int* n_tiles = meta + 24;
  int* tile_e = meta + 32;
  int* tile_row0 = meta + 32 + MAXTILES;

  hipMemsetAsync(out, 0, (size_t)TOKENS * DM * sizeof(float), stream);

  gate_topk<<<TOKENS / 4, 256, 0, stream>>>(x0, Wg, eids);
  count_prefix<<<1, 256, 0, stream>>>(eids, counts, offsets, cursors, n_tiles, tile_e, tile_row0);
  scatter_tokens<<<TOKENS / 256, 256, 0, stream>>>(eids, cursors, list);

  if (big) {
    conv_xl_kernel<<<(TOKENS * DM / 8) / 256, 256, 0, stream>>>(xl, xlb);
    for (int c = 0; c < NCHUNK; ++c) {
      conv_w1_kernel<<<dim3(CHUNK / 32, DM / 32, NE), 256, 0, stream>>>(W1, w1c, c * CHUNK);
      ffn1b_kernel<<<dim3(CHUNK / 128, MAXTILES), 256, 0, stream>>>(
          xlb, w1c, b1, list, counts, offsets, n_tiles, tile_e, tile_row0, Hc, c * CHUNK);
      conv_w2_kernel<<<dim3(DM / 32, CHUNK / 32, NE), 256, 0, stream>>>(W2, w2c, c * CHUNK);
      ffn2b_kernel<<<dim3(DM / 128, MAXTILES), 256, 0, stream>>>(
          Hc, w2c, b2, list, counts, offsets, n_tiles, tile_e, tile_row0, out, c * CHUNK);
    }
  } else {
    for (int c = 0; c < NCHUNK; ++c) {
      ffn1_kernel<<<dim3(CHUNK / 128, MAXTILES), 256, 0, stream>>>(
          xl, W1, b1, list, counts, offsets, n_tiles, tile_e, tile_row0, Hc, c * CHUNK);
      ffn2_kernel<<<dim3(DM / 128, MAXTILES), 256, 0, stream>>>(
          Hc, W2, b2, list, counts, offsets, n_tiles, tile_e, tile_row0, out, c * CHUNK);
    }
  }
}

// Round 2
// 939.276 us; speedup vs baseline: 1.5696x; 1.1651x over previous
//
#include <hip/hip_runtime.h>
#include <cstdint>
#include <cstddef>

// SparseMoE MI355X gfx950. ALL I/O FP32; bf16 MFMA internally.
// v3: 2-phase double-buffered LDS pipeline (catalog T3-minimum) in both ffn GEMMs:
//     stage(next K-tile) issued BEFORE compute(current), single barrier per K-step,
//     so the barrier's vmcnt(0) drain is covered by MFMA+ds_read instead of raw latency.
//     Plus ws-adaptive tiers: if ws allows, convert W1/W2 to bf16 ONCE (full transposed)
//     and enlarge the DH chunk (up to 4096) -> deeper ffn2 K-loop, 4x fewer atomic passes.
//
// tiers (chosen by ws_size):
//   full CL=4096: Hc 134M | xlb 16.8M | w1c 67M | w2c 67M | tail ~0.1M  (~285MB)
//   full CL=2048: Hc 67M  | ... (~218MB)      full CL=1024: Hc 33.5M (~185MB)
//   panel CL=1024 (floor, known-available): Hc 33.5M | xlb 16.8M | w1c 16.8M | w2c 16.8M (~84MB)

#define TOKENS 8192
#define DM 1024
#define DH 4096
#define NE 8
#define CHUNK 1024
#define MAXTILES 160

typedef __attribute__((ext_vector_type(8))) short short8;
typedef __attribute__((ext_vector_type(4))) float f32x4;
typedef unsigned short u16;
typedef unsigned int u32;
typedef unsigned long long u64;

__device__ __forceinline__ u16 f2bf(float f) {
  u32 u = __builtin_bit_cast(u32, f);
  u += 0x7fffu + ((u >> 16) & 1u);  // RNE
  return (u16)(u >> 16);
}

// async global->LDS, 16B per lane. LDS dest is wave-uniform base + lane*16 (m104).
__device__ __forceinline__ void gl2lds16(const void* g, void* l) {
  __builtin_amdgcn_global_load_lds(
      (const __attribute__((address_space(1))) void*)g,
      (__attribute__((address_space(3))) void*)l, 16, 0, 0);
}

// ---------------- gating: top-2 of fp32 logits (softmax monotone, gates > 0). No atomics.
__global__ __launch_bounds__(256) void gate_topk(
    const float* __restrict__ x0, const float* __restrict__ Wg,
    int* __restrict__ eids) {
  const int wave = threadIdx.x >> 6;
  const int lane = threadIdx.x & 63;
  const int t = blockIdx.x * 4 + wave;
  const float* xrow = x0 + (size_t)t * DM + lane * 16;
  float xs[16];
#pragma unroll
  for (int q = 0; q < 4; ++q) *(float4*)(xs + q * 4) = *(const float4*)(xrow + q * 4);
  float s[NE] = {0.f, 0.f, 0.f, 0.f, 0.f, 0.f, 0.f, 0.f};
#pragma unroll
  for (int j = 0; j < 16; ++j) {
    const float* wrow = Wg + (size_t)(lane * 16 + j) * NE;
    float w[8];
    *(float4*)(w) = *(const float4*)(wrow);
    *(float4*)(w + 4) = *(const float4*)(wrow + 4);
#pragma unroll
    for (int e = 0; e < NE; ++e) s[e] += xs[j] * w[e];
  }
#pragma unroll
  for (int off = 32; off > 0; off >>= 1)
#pragma unroll
    for (int e = 0; e < NE; ++e) s[e] += __shfl_down(s[e], off);
  if (lane == 0) {
    int a1 = 0; float v1 = s[0];
#pragma unroll
    for (int e = 1; e < NE; ++e) if (s[e] > v1) { v1 = s[e]; a1 = e; }  // first-index ties
    int a2 = -1; float v2 = 0.f; bool init = false;
#pragma unroll
    for (int e = 0; e < NE; ++e) {
      if (e == a1) continue;
      if (!init || s[e] > v2) { v2 = s[e]; a2 = e; init = true; }
    }
    eids[t] = a1 | (a2 << 8);
  }
}

// counts (ballot/popc) + offsets/cursors + expert-pure 128-row tile list.
__global__ __launch_bounds__(256) void count_prefix(
    const int* __restrict__ eids, int* __restrict__ counts, int* __restrict__ offsets,
    int* __restrict__ cursors, int* __restrict__ n_tiles,
    int* __restrict__ tile_e, int* __restrict__ tile_row0) {
  __shared__ int wc[4][NE];
  const int lane = threadIdx.x & 63;
  const int wave = threadIdx.x >> 6;
  int c[NE] = {0, 0, 0, 0, 0, 0, 0, 0};
  for (int t = threadIdx.x; t < TOKENS; t += 256) {
    int p = eids[t];
    int a1 = p & 255, a2 = (p >> 8) & 255;
#pragma unroll
    for (int e = 0; e < NE; ++e)
      c[e] += __popcll(__ballot(a1 == e)) + __popcll(__ballot(a2 == e));
  }
  if (lane == 0)
#pragma unroll
    for (int e = 0; e < NE; ++e) wc[wave][e] = c[e];
  __syncthreads();
  if (threadIdx.x == 0) {
    int o = 0, nt = 0;
    for (int e = 0; e < NE; ++e) {
      int ce = wc[0][e] + wc[1][e] + wc[2][e] + wc[3][e];
      counts[e] = ce; offsets[e] = o; cursors[e] = o;
      for (int r = 0; r < ce; r += 128) { tile_e[nt] = e; tile_row0[nt] = r; ++nt; }
      o += ce;
    }
    *n_tiles = nt;
  }
}

// wave-aggregated scatter: 1 atomic per (wave, expert).
__global__ __launch_bounds__(256) void scatter_tokens(
    const int* __restrict__ eids, int* __restrict__ cursors, int* __restrict__ list) {
  const int t = blockIdx.x * 256 + threadIdx.x;
  const int lane = threadIdx.x & 63;
  const int p = eids[t];
  const int a1 = p & 255, a2 = (p >> 8) & 255;
  const u64 lt = (1ull << lane) - 1ull;
#pragma unroll
  for (int e = 0; e < NE; ++e) {
    u64 b1 = __ballot(a1 == e);
    u64 b2 = __ballot(a2 == e);
    int tot = __popcll(b1) + __popcll(b2);
    int base = 0;
    if (lane == 0 && tot) base = atomicAdd(&cursors[e], tot);
    base = __shfl(base, 0);
    if (a1 == e) list[base + __popcll(b1 & lt)] = t;
    if (a2 == e) list[base + __popcll(b1) + __popcll(b2 & lt)] = t;
  }
}

// ---------------- conversions ----------------
__global__ __launch_bounds__(256) void conv_xl_kernel(
    const float* __restrict__ x, u16* __restrict__ xb) {
  size_t i = ((size_t)blockIdx.x * 256 + threadIdx.x) * 8;
  float4 a = *(const float4*)(x + i);
  float4 b = *(const float4*)(x + i + 4);
  u16 h[8];
  h[0] = f2bf(a.x); h[1] = f2bf(a.y); h[2] = f2bf(a.z); h[3] = f2bf(a.w);
  h[4] = f2bf(b.x); h[5] = f2bf(b.y); h[6] = f2bf(b.z); h[7] = f2bf(b.w);
  *(uint4*)(xb + i) = *(uint4*)h;
}

// W1 [e][DM][DH] fp32 -> w1c [e][n][k<DM] bf16 (transposed; n spans grid.x*32 cols at cb)
__global__ __launch_bounds__(256) void conv_w1_kernel(
    const float* __restrict__ W1, u16* __restrict__ w1c, int cb, size_t estride) {
  __shared__ float tile[32][33];
  const int e = blockIdx.z;
  const int n0 = blockIdx.x * 32;
  const int k0 = blockIdx.y * 32;
  const int tx = threadIdx.x & 31;
  const int ty = threadIdx.x >> 5;
#pragma unroll
  for (int j = 0; j < 4; ++j)
    tile[ty + j * 8][tx] = W1[((size_t)e * DM + k0 + ty + j * 8) * DH + cb + n0 + tx];
  __syncthreads();
#pragma unroll
  for (int j = 0; j < 4; ++j)
    w1c[(size_t)e * estride + (size_t)(n0 + ty + j * 8) * DM + k0 + tx] = f2bf(tile[tx][ty + j * 8]);
}

// W2 [e][DH][DM] fp32 -> w2c [e][n<DM][k] bf16 (transposed; k spans grid.y*32 at cb; k-stride kd)
__global__ __launch_bounds__(256) void conv_w2_kernel(
    const float* __restrict__ W2, u16* __restrict__ w2c, int cb, size_t estride, int kd) {
  __shared__ float tile[32][33];
  const int e = blockIdx.z;
  const int n0 = blockIdx.x * 32;
  const int k0 = blockIdx.y * 32;
  const int tx = threadIdx.x & 31;
  const int ty = threadIdx.x >> 5;
#pragma unroll
  for (int j = 0; j < 4; ++j)
    tile[ty + j * 8][tx] = W2[((size_t)e * DH + cb + k0 + ty + j * 8) * DM + n0 + tx];
  __syncthreads();
#pragma unroll
  for (int j = 0; j < 4; ++j)
    w2c[(size_t)e * estride + (size_t)(n0 + ty + j * 8) * kd + k0 + tx] = f2bf(tile[tx][ty + j * 8]);
}

// ---------------- ffn1: Hc[slot][n] = relu(xlb[tok] @ w1c^T + b1), 2-phase dbuf pipeline.
__global__ __launch_bounds__(256) void ffn1b_kernel(
    const u16* __restrict__ xlb, const u16* __restrict__ w1c,
    const float* __restrict__ b1, const int* __restrict__ list,
    const int* __restrict__ counts, const int* __restrict__ offsets,
    const int* __restrict__ n_tiles, const int* __restrict__ tile_e,
    const int* __restrict__ tile_row0, u16* __restrict__ Hc,
    int cbase, int bnbase, size_t ebstride, int hstride) {
  const int ti = blockIdx.y;
  if (ti >= *n_tiles) return;
  const int e = tile_e[ti];
  const int row0 = tile_row0[ti];
  const int cnt = counts[e];
  const int off = offsets[e];
  const int n0 = blockIdx.x * 128;

  __shared__ u16 As[2][128 * 64];   // 2 x 16KB
  __shared__ u16 Bs[2][128 * 64];   // 2 x 16KB

  const int tid = threadIdx.x;
  const int lane = tid & 63;
  const int wave = tid >> 6;
  const int wm = (wave & 1) * 64;
  const int wn = (wave >> 1) * 64;

  const int srow = lane >> 3;                    // row within 8-row group (== r&7)
  const int schunk = ((lane & 7) ^ srow) << 3;   // pre-swizzled source chunk (rule #21)

  const u16* aptr[4];
#pragma unroll
  for (int i = 0; i < 4; ++i) {
    int rr = row0 + wave * 32 + i * 8 + srow;
    if (rr >= cnt) rr = cnt - 1;                 // clamp; stores guarded later
    aptr[i] = xlb + (size_t)list[off + rr] * DM + schunk;
  }
  const u16* bptr = w1c + (size_t)e * ebstride +
                    (size_t)(bnbase + n0 + wave * 32 + srow) * DM + schunk;

  f32x4 acc[4][4];
#pragma unroll
  for (int mi = 0; mi < 4; ++mi)
#pragma unroll
    for (int ni = 0; ni < 4; ++ni) acc[mi][ni] = (f32x4){0.f, 0.f, 0.f, 0.f};

  // prologue: stage K-tile 0 into buf 0
#pragma unroll
  for (int i = 0; i < 4; ++i) {
    gl2lds16(aptr[i], &As[0][(wave * 32 + i * 8) * 64]);
    gl2lds16(bptr + (size_t)(i * 8) * DM, &Bs[0][(wave * 32 + i * 8) * 64]);
  }
  __syncthreads();

  int cur = 0;
  for (int k0 = 0; k0 < DM; k0 += 64) {
    if (k0 + 64 < DM) {                          // stage NEXT tile before compute
      const int nb = cur ^ 1;
#pragma unroll
      for (int i = 0; i < 4; ++i) {
        gl2lds16(aptr[i] + k0 + 64, &As[nb][(wave * 32 + i * 8) * 64]);
        gl2lds16(bptr + (size_t)(i * 8) * DM + k0 + 64, &Bs[nb][(wave * 32 + i * 8) * 64]);
      }
    }
    const u16* Ac = As[cur];
    const u16* Bc = Bs[cur];
#pragma unroll
    for (int s = 0; s < 2; ++s) {
      const int G = s * 4 + (lane >> 4);
      short8 af[4], bfr[4];
#pragma unroll
      for (int mi = 0; mi < 4; ++mi) {
        int r = wm + mi * 16 + (lane & 15);
        af[mi] = *(const short8*)(&Ac[r * 64 + ((G ^ (r & 7)) << 3)]);
      }
#pragma unroll
      for (int ni = 0; ni < 4; ++ni) {
        int r = wn + ni * 16 + (lane & 15);
        bfr[ni] = *(const short8*)(&Bc[r * 64 + ((G ^ (r & 7)) << 3)]);
      }
#pragma unroll
      for (int mi = 0; mi < 4; ++mi)
#pragma unroll
        for (int ni = 0; ni < 4; ++ni)
          acc[mi][ni] = __builtin_amdgcn_mfma_f32_16x16x32_bf16(af[mi], bfr[ni], acc[mi][ni], 0, 0, 0);
    }
    __syncthreads();   // drains: next-buf stages complete (vmcnt) + cur reads done (lgkmcnt)
    cur ^= 1;
  }

  float bb[4];
#pragma unroll
  for (int ni = 0; ni < 4; ++ni)
    bb[ni] = b1[e * DH + cbase + n0 + wn + ni * 16 + (lane & 15)];
#pragma unroll
  for (int mi = 0; mi < 4; ++mi) {
#pragma unroll
    for (int r = 0; r < 4; ++r) {
      int rrow = row0 + wm + mi * 16 + (lane >> 4) * 4 + r;
      if (rrow < cnt) {
        u16* h = Hc + (size_t)(off + rrow) * hstride + n0 + wn + (lane & 15);
#pragma unroll
        for (int ni = 0; ni < 4; ++ni) {
          float v = acc[mi][ni][r] + bb[ni];
          h[ni * 16] = f2bf(v > 0.f ? v : 0.f);
        }
      }
    }
  }
}

// ---------------- ffn2: out[tok][n] += Hc[slot] @ w2c^T (+b2 once per slot), 2-phase dbuf.
__global__ __launch_bounds__(256) void ffn2b_kernel(
    const u16* __restrict__ Hc, const u16* __restrict__ w2c,
    const float* __restrict__ b2, const int* __restrict__ list,
    const int* __restrict__ counts, const int* __restrict__ offsets,
    const int* __restrict__ n_tiles, const int* __restrict__ tile_e,
    const int* __restrict__ tile_row0, float* __restrict__ out,
    int clen, int kbase, size_t eb2, int kd2, int hstride, int addb2) {
  const int ti = blockIdx.y;
  if (ti >= *n_tiles) return;
  const int e = tile_e[ti];
  const int row0 = tile_row0[ti];
  const int cnt = counts[e];
  const int off = offsets[e];
  const int n0 = blockIdx.x * 128;

  __shared__ u16 As[2][128 * 64];
  __shared__ u16 Bs[2][128 * 64];

  const int tid = threadIdx.x;
  const int lane = tid & 63;
  const int wave = tid >> 6;
  const int wm = (wave & 1) * 64;
  const int wn = (wave >> 1) * 64;

  const int srow = lane >> 3;
  const int schunk = ((lane & 7) ^ srow) << 3;

  const u16* aptr[4];
#pragma unroll
  for (int i = 0; i < 4; ++i) {
    int rr = row0 + wave * 32 + i * 8 + srow;
    if (rr >= cnt) rr = cnt - 1;
    aptr[i] = Hc + (size_t)(off + rr) * hstride + schunk;
  }
  const u16* bptr = w2c + (size_t)e * eb2 +
                    (size_t)(n0 + wave * 32 + srow) * kd2 + kbase + schunk;

  f32x4 acc[4][4];
#pragma unroll
  for (int mi = 0; mi < 4; ++mi)
#pragma unroll
    for (int ni = 0; ni < 4; ++ni) acc[mi][ni] = (f32x4){0.f, 0.f, 0.f, 0.f};

#pragma unroll
  for (int i = 0; i < 4; ++i) {
    gl2lds16(aptr[i], &As[0][(wave * 32 + i * 8) * 64]);
    gl2lds16(bptr + (size_t)(i * 8) * kd2, &Bs[0][(wave * 32 + i * 8) * 64]);
  }
  __syncthreads();

  int cur = 0;
  for (int k0 = 0; k0 < clen; k0 += 64) {
    if (k0 + 64 < clen) {
      const int nb = cur ^ 1;
#pragma unroll
      for (int i = 0; i < 4; ++i) {
        gl2lds16(aptr[i] + k0 + 64, &As[nb][(wave * 32 + i * 8) * 64]);
        gl2lds16(bptr + (size_t)(i * 8) * kd2 + k0 + 64, &Bs[nb][(wave * 32 + i * 8) * 64]);
      }
    }
    const u16* Ac = As[cur];
    const u16* Bc = Bs[cur];
#pragma unroll
    for (int s = 0; s < 2; ++s) {
      const int G = s * 4 + (lane >> 4);
      short8 af[4], bfr[4];
#pragma unroll
      for (int mi = 0; mi < 4; ++mi) {
        int r = wm + mi * 16 + (lane & 15);
        af[mi] = *(const short8*)(&Ac[r * 64 + ((G ^ (r & 7)) << 3)]);
      }
#pragma unroll
      for (int ni = 0; ni < 4; ++ni) {
        int r = wn + ni * 16 + (lane & 15);
        bfr[ni] = *(const short8*)(&Bc[r * 64 + ((G ^ (r & 7)) << 3)]);
      }
#pragma unroll
      for (int mi = 0; mi < 4; ++mi)
#pragma unroll
        for (int ni = 0; ni < 4; ++ni)
          acc[mi][ni] = __builtin_amdgcn_mfma_f32_16x16x32_bf16(af[mi], bfr[ni], acc[mi][ni], 0, 0, 0);
    }
    __syncthreads();
    cur ^= 1;
  }

  float bb[4];
#pragma unroll
  for (int ni = 0; ni < 4; ++ni)
    bb[ni] = addb2 ? b2[e * DM + n0 + wn + ni * 16 + (lane & 15)] : 0.f;
#pragma unroll
  for (int mi = 0; mi < 4; ++mi) {
#pragma unroll
    for (int r = 0; r < 4; ++r) {
      int rrow = row0 + wm + mi * 16 + (lane >> 4) * 4 + r;
      if (rrow < cnt) {
        int tok = list[off + rrow];
        float* ar = out + (size_t)tok * DM + n0 + wn + (lane & 15);
#pragma unroll
        for (int ni = 0; ni < 4; ++ni)
          atomicAdd(&ar[ni * 16], acc[mi][ni][r] + bb[ni]);
      }
    }
  }
}

extern "C" void kernel_launch(void* const* d_in, const int* in_sizes, int n_in,
                              void* d_out, int out_size, void* d_ws, size_t ws_size,
                              hipStream_t stream) {
  const float* xl = (const float*)d_in[0];
  const float* x0 = (const float*)d_in[1];
  const float* Wg = (const float*)d_in[2];
  const float* W1 = (const float*)d_in[3];
  const float* b1 = (const float*)d_in[4];
  const float* W2 = (const float*)d_in[5];
  const float* b2 = (const float*)d_in[6];
  float* out = (float*)d_out;

  const size_t SZ_XLB = (size_t)TOKENS * DM * 2;                 // 16.8 MB
  const size_t SZ_TAIL = 65536 + 32768 + 4096;
  const size_t SZ_WFULL = (size_t)2 * NE * DM * DH * 2;          // 134.2 MB (both)
  const size_t SZ_WPANEL = (size_t)2 * NE * CHUNK * DM * 2;      // 33.6 MB (both)

  int CL; bool fullw;
  if (ws_size >= (size_t)2 * TOKENS * 4096 * 2 + SZ_XLB + SZ_WFULL + SZ_TAIL) { CL = 4096; fullw = true; }
  else if (ws_size >= (size_t)2 * TOKENS * 2048 * 2 + SZ_XLB + SZ_WFULL + SZ_TAIL) { CL = 2048; fullw = true; }
  else if (ws_size >= (size_t)2 * TOKENS * 1024 * 2 + SZ_XLB + SZ_WFULL + SZ_TAIL) { CL = 1024; fullw = true; }
  else { CL = 1024; fullw = false; }                             // 84 MB floor (known available)

  const size_t SZ_HC = (size_t)2 * TOKENS * CL * 2;
  const size_t SZ_W1C = fullw ? (size_t)NE * DH * DM * 2 : (size_t)NE * CHUNK * DM * 2;
  const size_t SZ_W2C = SZ_W1C;

  char* ws = (char*)d_ws;
  u16* Hc  = (u16*)ws;
  u16* xlb = (u16*)(ws + SZ_HC);
  u16* w1c = (u16*)(ws + SZ_HC + SZ_XLB);
  u16* w2c = (u16*)(ws + SZ_HC + SZ_XLB + SZ_W1C);
  int* list = (int*)(ws + SZ_HC + SZ_XLB + SZ_W1C + SZ_W2C);
  int* eids = (int*)((char*)list + 65536);
  int* meta = (int*)((char*)eids + 32768);
  int* counts = meta;
  int* offsets = meta + 8;
  int* cursors = meta + 16;
  int* n_tiles = meta + 24;
  int* tile_e = meta + 32;
  int* tile_row0 = meta + 32 + MAXTILES;

  hipMemsetAsync(out, 0, (size_t)TOKENS * DM * sizeof(float), stream);

  gate_topk<<<TOKENS / 4, 256, 0, stream>>>(x0, Wg, eids);
  count_prefix<<<1, 256, 0, stream>>>(eids, counts, offsets, cursors, n_tiles, tile_e, tile_row0);
  scatter_tokens<<<TOKENS / 256, 256, 0, stream>>>(eids, cursors, list);
  conv_xl_kernel<<<(TOKENS * DM / 8) / 256, 256, 0, stream>>>(xl, xlb);

  if (fullw) {
    conv_w1_kernel<<<dim3(DH / 32, DM / 32, NE), 256, 0, stream>>>(
        W1, w1c, 0, (size_t)DH * DM);
    conv_w2_kernel<<<dim3(DM / 32, DH / 32, NE), 256, 0, stream>>>(
        W2, w2c, 0, (size_t)DM * DH, DH);
    const int nch = DH / CL;
    for (int c = 0; c < nch; ++c) {
      ffn1b_kernel<<<dim3(CL / 128, MAXTILES), 256, 0, stream>>>(
          xlb, w1c, b1, list, counts, offsets, n_tiles, tile_e, tile_row0, Hc,
          c * CL, c * CL, (size_t)DH * DM, CL);
      ffn2b_kernel<<<dim3(DM / 128, MAXTILES), 256, 0, stream>>>(
          Hc, w2c, b2, list, counts, offsets, n_tiles, tile_e, tile_row0, out,
          CL, c * CL, (size_t)DM * DH, DH, CL, c == 0 ? 1 : 0);
    }
  } else {
    for (int c = 0; c < DH / CHUNK; ++c) {
      conv_w1_kernel<<<dim3(CHUNK / 32, DM / 32, NE), 256, 0, stream>>>(
          W1, w1c, c * CHUNK, (size_t)CHUNK * DM);
      ffn1b_kernel<<<dim3(CHUNK / 128, MAXTILES), 256, 0, stream>>>(
          xlb, w1c, b1, list, counts, offsets, n_tiles, tile_e, tile_row0, Hc,
          c * CHUNK, 0, (size_t)CHUNK * DM, CHUNK);
      conv_w2_kernel<<<dim3(DM / 32, CHUNK / 32, NE), 256, 0, stream>>>(
          W2, w2c, c * CHUNK, (size_t)DM * CHUNK, CHUNK);
      ffn2b_kernel<<<dim3(DM / 128, MAXTILES), 256, 0, stream>>>(
          Hc, w2c, b2, list, counts, offsets, n_tiles, tile_e, tile_row0, out,
          CHUNK, 0, (size_t)DM * CHUNK, CHUNK, CHUNK, c == 0 ? 1 : 0);
    }
  }
}